// Round 1
// baseline (443.491 us; speedup 1.0000x reference)
//
#include <hip/hip_runtime.h>

// SSIM (32,3,512,512) fp32, 11x11 Gaussian depthwise conv, SAME zero padding.
// Fused single-pass kernel: separable conv (11+11 taps), horizontal pass from
// LDS (x1,x2 interleaved float2 -> one ds_read_b64 per tap), vertical pass as
// register scatter into 5x16 accumulators, sqrt-free SSIM rational form.

#define IMG_H 512
#define IMG_W 512
#define N_IMGS 96              // 32 batch * 3 channels, depthwise-independent
#define TILE_W 64
#define TILE_H 16
#define HALO 5
#define KW 11
#define IN_ROWS (TILE_H + 2*HALO)   // 26
#define IN_COLS (TILE_W + 2*HALO)   // 74
#define COL_TILES (IMG_W / TILE_W)  // 8
#define ROW_TILES (IMG_H / TILE_H)  // 32
#define N_BLOCKS (N_IMGS * COL_TILES * ROW_TILES)  // 24576
#define NBINS 4096
#define TOTAL_PIX (32.0f * 3.0f * 512.0f * 512.0f)

__global__ __launch_bounds__(64) void ssim_main(
    const float* __restrict__ img1, const float* __restrict__ img2,
    const float* __restrict__ window, float* __restrict__ bins)
{
    __shared__ float2 s_in[IN_ROWS][IN_COLS];   // (x1, x2) interleaved

    const int tid = threadIdx.x;                 // 0..63, one thread per column

    // Recover the 1D gaussian: g2d[5][k] = g[5]*g[k]; g[5] = sqrt(g2d[5][5]).
    float g[KW];
    {
        const float inv = rsqrtf(window[5*KW + 5]);
        #pragma unroll
        for (int k = 0; k < KW; ++k) g[k] = window[5*KW + k] * inv;
    }

    // Decompose block index -> (image, row tile, col tile)
    const int b   = blockIdx.x;
    const int img = b >> 8;                      // / 256
    const int rem = b & 255;
    const int ty  = rem >> 3;                    // 0..31
    const int tx  = rem & 7;                     // 0..7
    const int y0  = ty * TILE_H;
    const int x0  = tx * TILE_W;

    const float* __restrict__ p1 = img1 + (size_t)img * (IMG_H * IMG_W);
    const float* __restrict__ p2 = img2 + (size_t)img * (IMG_H * IMG_W);

    // Cooperative load of the halo tile (zero pad outside the image).
    for (int idx = tid; idx < IN_ROWS * IN_COLS; idx += 64) {
        const int r  = idx / IN_COLS;
        const int c  = idx - r * IN_COLS;
        const int gy = y0 + r - HALO;
        const int gx = x0 + c - HALO;
        float a = 0.0f, bb = 0.0f;
        if (gy >= 0 && gy < IMG_H && gx >= 0 && gx < IMG_W) {
            const int o = gy * IMG_W + gx;
            a  = p1[o];
            bb = p2[o];
        }
        s_in[r][c] = make_float2(a, bb);
    }
    __syncthreads();

    // Per-column accumulators for the 5 vertical convs (registers).
    float a_mu1[TILE_H], a_mu2[TILE_H], a_e11[TILE_H], a_e22[TILE_H], a_e12[TILE_H];
    #pragma unroll
    for (int r = 0; r < TILE_H; ++r) {
        a_mu1[r] = 0.f; a_mu2[r] = 0.f; a_e11[r] = 0.f; a_e22[r] = 0.f; a_e12[r] = 0.f;
    }

    const int c = tid;
    #pragma unroll
    for (int j = 0; j < IN_ROWS; ++j) {
        // Horizontal 11-tap conv of (x1, x2, x1^2, x2^2, x1*x2) at (row j, col c)
        float h1 = 0.f, h2 = 0.f, h11 = 0.f, h22 = 0.f, h12 = 0.f;
        #pragma unroll
        for (int k = 0; k < KW; ++k) {
            const float2 v = s_in[j][c + k];
            const float t1 = g[k] * v.x;
            const float t2 = g[k] * v.y;
            h1  += t1;
            h2  += t2;
            h11 += t1 * v.x;
            h22 += t2 * v.y;
            h12 += t1 * v.y;
        }
        // Vertical scatter: row j contributes to output rows r = j-d, d = 0..10
        #pragma unroll
        for (int d = 0; d < KW; ++d) {
            const int r = j - d;
            if (r >= 0 && r < TILE_H) {
                const float gv = g[d];
                a_mu1[r] += gv * h1;
                a_mu2[r] += gv * h2;
                a_e11[r] += gv * h11;
                a_e22[r] += gv * h22;
                a_e12[r] += gv * h12;
            }
        }
    }

    // SSIM per pixel (sqrt-free form; s1*s2 factor cancels exactly) + sum.
    const float C1 = 1e-4f;     // (0.01*1.0)^2
    const float C2 = 9e-4f;     // (0.03*1.0)^2
    float sum = 0.f;
    #pragma unroll
    for (int r = 0; r < TILE_H; ++r) {
        const float mu1 = a_mu1[r], mu2 = a_mu2[r];
        const float mu1s = mu1 * mu1, mu2s = mu2 * mu2, mu12 = mu1 * mu2;
        const float s1  = fmaxf(a_e11[r] - mu1s, 0.f);
        const float s2  = fmaxf(a_e22[r] - mu2s, 0.f);
        const float s12 = a_e12[r] - mu12;
        const float num = (2.f * mu12 + C1) * (2.f * s12 + C2);
        const float den = (mu1s + mu2s + C1) * (s1 + s2 + C2);
        sum += num * __builtin_amdgcn_rcpf(den);
    }

    // Wave (=block) reduction, then one atomic per block into a bin.
    #pragma unroll
    for (int off = 32; off > 0; off >>= 1)
        sum += __shfl_down(sum, off, 64);
    if (tid == 0)
        atomicAdd(&bins[b & (NBINS - 1)], sum);
}

__global__ __launch_bounds__(64) void ssim_final(
    const float* __restrict__ bins, float* __restrict__ out)
{
    const int tid = threadIdx.x;
    float s = 0.f;
    for (int i = tid; i < NBINS; i += 64) s += bins[i];
    #pragma unroll
    for (int off = 32; off > 0; off >>= 1)
        s += __shfl_down(s, off, 64);
    if (tid == 0) out[0] = s * (1.0f / TOTAL_PIX);
}

extern "C" void kernel_launch(void* const* d_in, const int* in_sizes, int n_in,
                              void* d_out, int out_size, void* d_ws, size_t ws_size,
                              hipStream_t stream) {
    const float* img1   = (const float*)d_in[0];
    const float* img2   = (const float*)d_in[1];
    const float* window = (const float*)d_in[2];
    float* bins = (float*)d_ws;
    float* out  = (float*)d_out;

    hipMemsetAsync(bins, 0, NBINS * sizeof(float), stream);
    ssim_main<<<N_BLOCKS, 64, 0, stream>>>(img1, img2, window, bins);
    ssim_final<<<1, 64, 0, stream>>>(bins, out);
}